// Round 8
// baseline (348.493 us; speedup 1.0000x reference)
//
#include <hip/hip_runtime.h>

// Histogram2D: x (16, 131072, 2) f32 in [0,1) -> counts (16, 100, 100) f32, normalized.
// Round 7 model: LDS atomic engine = ~3 cyc per 32-bit LANE-SLOT, serial per CU
// (u64 = 2 slots, r6). VMEM/L2 RMW engine is idle -> SPLIT: plus-shape 5 sites
// (always fire) -> LDS ds_add_u32; 4 corners (~50%) + 2 far (~25%) -> fire-and-forget
// global_atomic_add_u32 into the block's PRIVATE partial row (no contention).
// Flush: LDS hist atomically added into the same row (row pre-zeroed by memset).
// Exact batch totals: LDS sum + in-register sum of offloaded quanta -> u64 atomic.
// All masked branchy (r4 form beat branchless by ~25%). Values bit-identical to r5/r6.

#define BINS     100
#define NBINS2   (BINS * BINS)     // 10000
#define NQUAD    (NBINS2 / 4)      // 2500
#define NPOINTS  131072
#define NBATCH   16
#define PPB      32                // partial blocks per batch
#define CHUNK    (NPOINTS / PPB)   // 4096 points per block
#define THREADS  1024
#define NPART    (NBATCH * PPB)    // 512
#define QSCALE   33554432.0f       // 2^25 fixed-point scale
#define QINV     (1.0 / 33554432.0)

// returns sum of quanta offloaded to global (for exact totals)
__device__ __forceinline__ unsigned accum_point_split(
    unsigned* lh, unsigned* __restrict__ gp, float x0, float x1)
{
    // anchor bin: floor(x*100) clipped
    int i0 = __float2int_rd(__fmul_rn(x0, 100.0f)); i0 = min(max(i0, 0), BINS - 1);
    int i1 = __float2int_rd(__fmul_rn(x1, 100.0f)); i1 = min(max(i1, 0), BINS - 1);
    const float fi0 = (float)i0, fi1 = (float)i1;
    const float c00 = __fmul_rn(0.01f, fi0 + 0.5f);
    const float c10 = __fmul_rn(0.01f, fi1 + 0.5f);
    const float e00 = fabsf(__fsub_rn(x0, c00));
    const float e10 = fabsf(__fsub_rn(x1, c10));
    float e0m = fabsf(__fsub_rn(x0, __fmul_rn(0.01f, fi0 - 0.5f)));
    float e0p = fabsf(__fsub_rn(x0, __fmul_rn(0.01f, fi0 + 1.5f)));
    float e1m = fabsf(__fsub_rn(x1, __fmul_rn(0.01f, fi1 - 0.5f)));
    float e1p = fabsf(__fsub_rn(x1, __fmul_rn(0.01f, fi1 + 1.5f)));
    e0m = (i0 > 0)        ? e0m : 1e9f;   // OOB -> w < 0 -> masked off
    e0p = (i0 < BINS - 1) ? e0p : 1e9f;
    e1m = (i1 > 0)        ? e1m : 1e9f;
    e1p = (i1 < BINS - 1) ? e1p : 1e9f;
    // only the leaned-toward +/-2 offset can fire, paired with the other coord's own bin
    const bool up0 = (x0 > c00), up1 = (x1 > c10);
    const int   f0  = up0 ? i0 + 2 : i0 - 2;
    const int   f1  = up1 ? i1 + 2 : i1 - 2;
    const float ff0 = up0 ? fi0 + 2.0f : fi0 - 2.0f;
    const float ff1 = up1 ? fi1 + 2.0f : fi1 - 2.0f;
    float e0f = fabsf(__fsub_rn(x0, __fmul_rn(0.01f, ff0 + 0.5f)));
    float e1f = fabsf(__fsub_rn(x1, __fmul_rn(0.01f, ff1 + 0.5f)));
    e0f = ((unsigned)f0 < (unsigned)BINS) ? e0f : 1e9f;
    e1f = ((unsigned)f1 < (unsigned)BINS) ? e1f : 1e9f;

    const int rm = max(i0 - 1, 0) * BINS;
    const int r0 = i0 * BINS;
    const int rp = min(i0 + 1, BINS - 1) * BINS;
    const int rf = min(max(f0, 0), BINS - 1) * BINS;
    const int cm = max(i1 - 1, 0);
    const int cc = i1;
    const int cp = min(i1 + 1, BINS - 1);
    const int cf = min(max(f1, 0), BINS - 1);

    // plus-shape -> LDS atomic engine (masked branchy, r4 form)
#define SITEL(EA, EB, ADDR) do {                                               \
        const float w_ = fmaf(-0.5f, __fadd_rn(EA, EB), 0.01f);                \
        if (w_ > 0.0f)                                                         \
            atomicAdd(&lh[ADDR], (unsigned)fmaf(w_, QSCALE, 0.5f));            \
    } while (0)
    SITEL(e0m, e10, rm + cc);
    SITEL(e00, e1m, r0 + cm);
    SITEL(e00, e10, r0 + cc);
    SITEL(e00, e1p, r0 + cp);
    SITEL(e0p, e10, rp + cc);
#undef SITEL

    // corners + far -> L2 RMW engine (block-private row, fire-and-forget)
    unsigned off = 0u;
#define SITEG(EA, EB, ADDR) do {                                               \
        const float w_ = fmaf(-0.5f, __fadd_rn(EA, EB), 0.01f);                \
        if (w_ > 0.0f) {                                                       \
            const unsigned q_ = (unsigned)fmaf(w_, QSCALE, 0.5f);              \
            atomicAdd(&gp[ADDR], q_);                                          \
            off += q_;                                                         \
        }                                                                      \
    } while (0)
    SITEG(e0m, e1m, rm + cm); SITEG(e0m, e1p, rm + cp);
    SITEG(e0p, e1m, rp + cm); SITEG(e0p, e1p, rp + cp);
    SITEG(e0f, e10, rf + cc);
    SITEG(e00, e1f, r0 + cf);
#undef SITEG
    return off;
}

// ---- main path: split-engine hist; part row pre-zeroed; exact u64 batch totals ----
__global__ __launch_bounds__(THREADS) void hist_part_kernel(
    const float* __restrict__ x, unsigned* __restrict__ part,
    unsigned long long* __restrict__ totals)
{
    __shared__ __align__(16) unsigned lh[NBINS2];
    uint4* lh4 = (uint4*)lh;
    for (int i = threadIdx.x; i < NBINS2 / 4; i += THREADS)
        lh4[i] = make_uint4(0u, 0u, 0u, 0u);
    __syncthreads();

    const int b  = blockIdx.x / PPB;
    const int pb = blockIdx.x % PPB;
    unsigned* __restrict__ gp = part + (size_t)blockIdx.x * NBINS2;
    const float4* __restrict__ xp = reinterpret_cast<const float4*>(
        x + (size_t)b * (NPOINTS * 2) + (size_t)pb * (CHUNK * 2));

    unsigned offsum = 0u;   // <= 4 pts * 6 sites * 167773 quanta -> fits u32
    #pragma unroll
    for (int k = 0; k < (CHUNK / 2) / THREADS; ++k) {
        const float4 p = xp[threadIdx.x + k * THREADS];
        offsum += accum_point_split(lh, gp, p.x, p.y);
        offsum += accum_point_split(lh, gp, p.z, p.w);
    }
    __syncthreads();

    // flush LDS hist into the block's row (atomic: row also holds offloaded quanta)
    unsigned long long ts = (unsigned long long)offsum;
    for (int i = threadIdx.x; i < NBINS2; i += THREADS) {
        const unsigned v = lh[i];
        if (v) atomicAdd(&gp[i], v);
        ts += v;
    }
    #pragma unroll
    for (int off = 32; off > 0; off >>= 1) ts += __shfl_down(ts, off, 64);
    if ((threadIdx.x & 63) == 0) atomicAdd(&totals[b], ts);
}

// 160 blocks x 256 thr: thread owns one uint4 (4 bins); 32 coalesced 16B loads.
__global__ __launch_bounds__(256) void reduce_norm_kernel(
    const uint4* __restrict__ part4, const unsigned long long* __restrict__ totals,
    float4* __restrict__ out4)
{
    const int b    = blockIdx.x / 10;
    const int ch   = blockIdx.x % 10;
    const int quad = ch * 256 + threadIdx.x;   // 0..2559, 2500 active
    if (quad < NQUAD) {
        const uint4* __restrict__ pp = part4 + (size_t)b * PPB * NQUAD + quad;
        unsigned long long s0 = 0, s1 = 0, s2 = 0, s3 = 0;
        #pragma unroll
        for (int p = 0; p < PPB; ++p) {
            const uint4 v = pp[(size_t)p * NQUAD];
            s0 += v.x; s1 += v.y; s2 += v.z; s3 += v.w;
        }
        const double fac = QINV / ((double)totals[b] * QINV + 1e-5);
        out4[(size_t)b * NQUAD + quad] = make_float4(
            (float)((double)s0 * fac), (float)((double)s1 * fac),
            (float)((double)s2 * fac), (float)((double)s3 * fac));
    }
}

// ---- fallback path (ws too small): float LDS hist + global atomic flush ----
__device__ __forceinline__ void accum_point_f(float* lh, float x0, float x1) {
    int i0 = __float2int_rd(__fmul_rn(x0, 100.0f)); i0 = min(max(i0, 0), BINS - 1);
    int i1 = __float2int_rd(__fmul_rn(x1, 100.0f)); i1 = min(max(i1, 0), BINS - 1);
    const float fi0 = (float)i0, fi1 = (float)i1;
    const float c00 = __fmul_rn(0.01f, fi0 + 0.5f);
    const float c10 = __fmul_rn(0.01f, fi1 + 0.5f);
    const float e00 = fabsf(__fsub_rn(x0, c00));
    const float e10 = fabsf(__fsub_rn(x1, c10));
    float e0m = fabsf(__fsub_rn(x0, __fmul_rn(0.01f, fi0 - 0.5f)));
    float e0p = fabsf(__fsub_rn(x0, __fmul_rn(0.01f, fi0 + 1.5f)));
    float e1m = fabsf(__fsub_rn(x1, __fmul_rn(0.01f, fi1 - 0.5f)));
    float e1p = fabsf(__fsub_rn(x1, __fmul_rn(0.01f, fi1 + 1.5f)));
    e0m = (i0 > 0)        ? e0m : 1e9f;
    e0p = (i0 < BINS - 1) ? e0p : 1e9f;
    e1m = (i1 > 0)        ? e1m : 1e9f;
    e1p = (i1 < BINS - 1) ? e1p : 1e9f;
    const bool up0 = (x0 > c00), up1 = (x1 > c10);
    const int   f0  = up0 ? i0 + 2 : i0 - 2;
    const int   f1  = up1 ? i1 + 2 : i1 - 2;
    const float ff0 = up0 ? fi0 + 2.0f : fi0 - 2.0f;
    const float ff1 = up1 ? fi1 + 2.0f : fi1 - 2.0f;
    float e0f = fabsf(__fsub_rn(x0, __fmul_rn(0.01f, ff0 + 0.5f)));
    float e1f = fabsf(__fsub_rn(x1, __fmul_rn(0.01f, ff1 + 0.5f)));
    e0f = ((unsigned)f0 < (unsigned)BINS) ? e0f : 1e9f;
    e1f = ((unsigned)f1 < (unsigned)BINS) ? e1f : 1e9f;
    const int rm = max(i0 - 1, 0) * BINS;
    const int r0 = i0 * BINS;
    const int rp = min(i0 + 1, BINS - 1) * BINS;
    const int rf = min(max(f0, 0), BINS - 1) * BINS;
    const int cm = max(i1 - 1, 0);
    const int cc = i1;
    const int cp = min(i1 + 1, BINS - 1);
    const int cf = min(max(f1, 0), BINS - 1);
#define SITEF(EA, EB, ADDR) do {                                               \
        const float w_ = fmaf(-0.5f, __fadd_rn(EA, EB), 0.01f);                \
        if (w_ > 0.0f) unsafeAtomicAdd(&lh[ADDR], w_);                         \
    } while (0)
    SITEF(e0m, e1m, rm + cm); SITEF(e0m, e10, rm + cc); SITEF(e0m, e1p, rm + cp);
    SITEF(e00, e1m, r0 + cm); SITEF(e00, e10, r0 + cc); SITEF(e00, e1p, r0 + cp);
    SITEF(e0p, e1m, rp + cm); SITEF(e0p, e10, rp + cc); SITEF(e0p, e1p, rp + cp);
    SITEF(e0f, e10, rf + cc);
    SITEF(e00, e1f, r0 + cf);
#undef SITEF
}

__global__ __launch_bounds__(THREADS) void hist_accum_kernel(
    const float* __restrict__ x, float* __restrict__ out)
{
    __shared__ __align__(16) float lh[NBINS2];
    float4* lh4 = (float4*)lh;
    for (int i = threadIdx.x; i < NBINS2 / 4; i += THREADS)
        lh4[i] = make_float4(0.f, 0.f, 0.f, 0.f);
    __syncthreads();
    const int b  = blockIdx.x / PPB;
    const int pb = blockIdx.x % PPB;
    const float4* __restrict__ xp = reinterpret_cast<const float4*>(
        x + (size_t)b * (NPOINTS * 2) + (size_t)pb * (CHUNK * 2));
    #pragma unroll
    for (int k = 0; k < (CHUNK / 2) / THREADS; ++k) {
        const float4 p = xp[threadIdx.x + k * THREADS];
        accum_point_f(lh, p.x, p.y);
        accum_point_f(lh, p.z, p.w);
    }
    __syncthreads();
    float* __restrict__ ob = out + (size_t)b * NBINS2;
    for (int i = threadIdx.x; i < NBINS2; i += THREADS) {
        const float v = lh[i];
        if (v != 0.0f) unsafeAtomicAdd(&ob[i], v);
    }
}

__global__ __launch_bounds__(1024) void norm_kernel(float* __restrict__ out)
{
    const int b = blockIdx.x;
    float* __restrict__ h = out + (size_t)b * NBINS2;
    float local = 0.0f;
    for (int i = threadIdx.x; i < NBINS2; i += 1024) local += h[i];
    #pragma unroll
    for (int off = 32; off > 0; off >>= 1) local += __shfl_down(local, off, 64);
    __shared__ float wsum[16];
    __shared__ float sden;
    if ((threadIdx.x & 63) == 0) wsum[threadIdx.x >> 6] = local;
    __syncthreads();
    if (threadIdx.x == 0) {
        float tt = 0.f;
        #pragma unroll
        for (int i = 0; i < 16; ++i) tt += wsum[i];
        sden = __fadd_rn(tt, 1e-5f);
    }
    __syncthreads();
    const float den = sden;
    for (int i = threadIdx.x; i < NBINS2; i += 1024) h[i] = __fdiv_rn(h[i], den);
}

extern "C" void kernel_launch(void* const* d_in, const int* in_sizes, int n_in,
                              void* d_out, int out_size, void* d_ws, size_t ws_size,
                              hipStream_t stream) {
    (void)in_sizes; (void)n_in;
    const float* x = (const float*)d_in[0];
    float* out = (float*)d_out;

    const size_t need = 128 + (size_t)NPART * NBINS2 * sizeof(unsigned);
    if (ws_size >= need) {
        unsigned long long* totals = (unsigned long long*)d_ws;        // [16]
        unsigned* part = (unsigned*)((char*)d_ws + 128);               // [512][10000]
        // zero totals + partial rows (rows receive atomics from hist)
        hipMemsetAsync(d_ws, 0, need, stream);
        hist_part_kernel<<<NPART, THREADS, 0, stream>>>(x, part, totals);
        reduce_norm_kernel<<<NBATCH * 10, 256, 0, stream>>>(
            (const uint4*)part, totals, (float4*)out);
    } else {
        hipMemsetAsync(out, 0, (size_t)out_size * sizeof(float), stream);
        hist_accum_kernel<<<NPART, THREADS, 0, stream>>>(x, out);
        norm_kernel<<<NBATCH, 1024, 0, stream>>>(out);
    }
}

// Round 9
// 151.015 us; speedup vs baseline: 2.3077x; 2.3077x over previous
//
#include <hip/hip_runtime.h>

// Histogram2D: x (16, 131072, 2) f32 in [0,1) -> counts (16, 100, 100) f32, normalized.
// Round 9 model: (1) LDS atomic engine = 3.3 cyc per ISSUED 32-bit lane, serial per CU;
// exactly 8 sites fire/point (center 1 + edges 4 + corners 2 + far 2x0.5) -> scatter
// hist is at its ~90us floor. (2) r8: RANDOM global atomics = line-granular memory-side
// RMW (210MB HBM writes) - poison. r1: COALESCED global atomics = payload-granular
// (4B each) - cheap. (3) r5/r6's hidden cost: reduce read 20MB of partials at 330GB/s
// (~60us). Fix: flush LDS hist via coalesced global_atomic_add_u64 bin-pairs into a
// per-batch u32 accumulator (640KB, L2-resident; uniform data keeps bins ~60x under
// u32 overflow), so the reduce reads only 640KB. Quanta bit-identical to r5/r6.

#define BINS     100
#define NBINS2   (BINS * BINS)     // 10000
#define NPAIR    (NBINS2 / 2)      // 5000 u64 bin-pairs
#define NPOINTS  131072
#define NBATCH   16
#define PPB      32                // partial blocks per batch
#define CHUNK    (NPOINTS / PPB)   // 4096 points per block
#define THREADS  1024
#define NPART    (NBATCH * PPB)    // 512
#define QSCALE   33554432.0f       // 2^25 fixed-point scale
#define QINV     (1.0 / 33554432.0)

__device__ __forceinline__ void accum_point_q(unsigned* lh, float x0, float x1) {
    // anchor bin: floor(x*100) clipped (r5-verified numerics)
    int i0 = __float2int_rd(__fmul_rn(x0, 100.0f)); i0 = min(max(i0, 0), BINS - 1);
    int i1 = __float2int_rd(__fmul_rn(x1, 100.0f)); i1 = min(max(i1, 0), BINS - 1);
    const float fi0 = (float)i0, fi1 = (float)i1;
    const float c00 = __fmul_rn(0.01f, fi0 + 0.5f);
    const float c10 = __fmul_rn(0.01f, fi1 + 0.5f);
    const float e00 = fabsf(__fsub_rn(x0, c00));
    const float e10 = fabsf(__fsub_rn(x1, c10));
    float e0m = fabsf(__fsub_rn(x0, __fmul_rn(0.01f, fi0 - 0.5f)));
    float e0p = fabsf(__fsub_rn(x0, __fmul_rn(0.01f, fi0 + 1.5f)));
    float e1m = fabsf(__fsub_rn(x1, __fmul_rn(0.01f, fi1 - 0.5f)));
    float e1p = fabsf(__fsub_rn(x1, __fmul_rn(0.01f, fi1 + 1.5f)));
    e0m = (i0 > 0)        ? e0m : 1e9f;   // OOB -> w <= 0 -> +0 add / masked off
    e0p = (i0 < BINS - 1) ? e0p : 1e9f;
    e1m = (i1 > 0)        ? e1m : 1e9f;
    e1p = (i1 < BINS - 1) ? e1p : 1e9f;
    // only the leaned-toward +/-2 offset can fire, paired with the other coord's own bin
    const bool up0 = (x0 > c00), up1 = (x1 > c10);
    const int   f0  = up0 ? i0 + 2 : i0 - 2;
    const int   f1  = up1 ? i1 + 2 : i1 - 2;
    const float ff0 = up0 ? fi0 + 2.0f : fi0 - 2.0f;
    const float ff1 = up1 ? fi1 + 2.0f : fi1 - 2.0f;
    float e0f = fabsf(__fsub_rn(x0, __fmul_rn(0.01f, ff0 + 0.5f)));
    float e1f = fabsf(__fsub_rn(x1, __fmul_rn(0.01f, ff1 + 0.5f)));
    e0f = ((unsigned)f0 < (unsigned)BINS) ? e0f : 1e9f;
    e1f = ((unsigned)f1 < (unsigned)BINS) ? e1f : 1e9f;

    const int rm = max(i0 - 1, 0) * BINS;
    const int r0 = i0 * BINS;
    const int rp = min(i0 + 1, BINS - 1) * BINS;
    const int rf = min(max(f0, 0), BINS - 1) * BINS;
    const int cm = max(i1 - 1, 0);
    const int cc = i1;
    const int cp = min(i1 + 1, BINS - 1);
    const int cf = min(max(f1, 0), BINS - 1);

    // plus-shape: always fires when in-bounds -> unconditional (fmax clamps OOB to +0)
#define SITEU(EA, EB, ADDR) do {                                               \
        const float w_ = fmaxf(fmaf(-0.5f, __fadd_rn(EA, EB), 0.01f), 0.0f);   \
        atomicAdd(&lh[ADDR], (unsigned)fmaf(w_, QSCALE, 0.5f));                \
    } while (0)
    // corners (~50%) + far (~25-50%): masked -> only fired lanes hit the engine
#define SITEQ(EA, EB, ADDR) do {                                               \
        const float w_ = fmaf(-0.5f, __fadd_rn(EA, EB), 0.01f);                \
        if (w_ > 0.0f)                                                         \
            atomicAdd(&lh[ADDR], (unsigned)fmaf(w_, QSCALE, 0.5f));            \
    } while (0)
    SITEQ(e0m, e1m, rm + cm); SITEU(e0m, e10, rm + cc); SITEQ(e0m, e1p, rm + cp);
    SITEU(e00, e1m, r0 + cm); SITEU(e00, e10, r0 + cc); SITEU(e00, e1p, r0 + cp);
    SITEQ(e0p, e1m, rp + cm); SITEU(e0p, e10, rp + cc); SITEQ(e0p, e1p, rp + cp);
    SITEQ(e0f, e10, rf + cc);
    SITEQ(e00, e1f, r0 + cf);
#undef SITEU
#undef SITEQ
}

// ---- main path: LDS u32 hist -> COALESCED u64-pair atomic flush into per-batch
// accumulator (640KB total) + exact u64 batch totals ----
__global__ __launch_bounds__(THREADS) void hist_part_kernel(
    const float* __restrict__ x, unsigned* __restrict__ accum,
    unsigned long long* __restrict__ totals)
{
    __shared__ __align__(16) unsigned lh[NBINS2];
    uint4* lh4 = (uint4*)lh;
    for (int i = threadIdx.x; i < NBINS2 / 4; i += THREADS)
        lh4[i] = make_uint4(0u, 0u, 0u, 0u);
    __syncthreads();

    const int b  = blockIdx.x / PPB;
    const int pb = blockIdx.x % PPB;
    const float4* __restrict__ xp = reinterpret_cast<const float4*>(
        x + (size_t)b * (NPOINTS * 2) + (size_t)pb * (CHUNK * 2));

    #pragma unroll
    for (int k = 0; k < (CHUNK / 2) / THREADS; ++k) {
        const float4 p = xp[threadIdx.x + k * THREADS];
        accum_point_q(lh, p.x, p.y);
        accum_point_q(lh, p.z, p.w);
    }
    __syncthreads();

    // flush: 5000 coalesced u64 atomics per block into the batch's accum row.
    // Row byte offset b*40000 is 8B-aligned; consecutive lanes -> consecutive addrs.
    const uint2* __restrict__ lh2 = (const uint2*)lh;
    unsigned long long* __restrict__ acc2 =
        (unsigned long long*)(accum + (size_t)b * NBINS2);
    unsigned long long ts = 0ull;
    for (int i = threadIdx.x; i < NPAIR; i += THREADS) {
        const uint2 v = lh2[i];
        const unsigned long long pk =
            (unsigned long long)v.x | ((unsigned long long)v.y << 32);
        if (pk) atomicAdd(&acc2[i], pk);
        ts += (unsigned long long)v.x + v.y;
    }
    #pragma unroll
    for (int off = 32; off > 0; off >>= 1) ts += __shfl_down(ts, off, 64);
    if ((threadIdx.x & 63) == 0) atomicAdd(&totals[b], ts);
}

// 160 blocks x 256 thr: (b = blk/10, chunk = blk%10); one uint4 (4 bins)/thread.
// Reads only 640KB (L2-hot), normalizes in double, float4 store.
__global__ __launch_bounds__(256) void reduce_norm_kernel(
    const uint4* __restrict__ accum4, const unsigned long long* __restrict__ totals,
    float4* __restrict__ out4)
{
    const int b  = blockIdx.x / 10;
    const int ch = blockIdx.x % 10;
    const int t  = threadIdx.x;
    if (t < 250) {   // 250 uint4 = 1000 bins per chunk
        const int idx = b * (NBINS2 / 4) + ch * 250 + t;
        const uint4 v = accum4[idx];
        const double fac = QINV / ((double)totals[b] * QINV + 1e-5);
        out4[idx] = make_float4(
            (float)((double)v.x * fac), (float)((double)v.y * fac),
            (float)((double)v.z * fac), (float)((double)v.w * fac));
    }
}

// ---- fallback path (ws too small): float LDS hist + global atomic flush ----
__device__ __forceinline__ void accum_point_f(float* lh, float x0, float x1) {
    int i0 = __float2int_rd(__fmul_rn(x0, 100.0f)); i0 = min(max(i0, 0), BINS - 1);
    int i1 = __float2int_rd(__fmul_rn(x1, 100.0f)); i1 = min(max(i1, 0), BINS - 1);
    const float fi0 = (float)i0, fi1 = (float)i1;
    const float c00 = __fmul_rn(0.01f, fi0 + 0.5f);
    const float c10 = __fmul_rn(0.01f, fi1 + 0.5f);
    const float e00 = fabsf(__fsub_rn(x0, c00));
    const float e10 = fabsf(__fsub_rn(x1, c10));
    float e0m = fabsf(__fsub_rn(x0, __fmul_rn(0.01f, fi0 - 0.5f)));
    float e0p = fabsf(__fsub_rn(x0, __fmul_rn(0.01f, fi0 + 1.5f)));
    float e1m = fabsf(__fsub_rn(x1, __fmul_rn(0.01f, fi1 - 0.5f)));
    float e1p = fabsf(__fsub_rn(x1, __fmul_rn(0.01f, fi1 + 1.5f)));
    e0m = (i0 > 0)        ? e0m : 1e9f;
    e0p = (i0 < BINS - 1) ? e0p : 1e9f;
    e1m = (i1 > 0)        ? e1m : 1e9f;
    e1p = (i1 < BINS - 1) ? e1p : 1e9f;
    const bool up0 = (x0 > c00), up1 = (x1 > c10);
    const int   f0  = up0 ? i0 + 2 : i0 - 2;
    const int   f1  = up1 ? i1 + 2 : i1 - 2;
    const float ff0 = up0 ? fi0 + 2.0f : fi0 - 2.0f;
    const float ff1 = up1 ? fi1 + 2.0f : fi1 - 2.0f;
    float e0f = fabsf(__fsub_rn(x0, __fmul_rn(0.01f, ff0 + 0.5f)));
    float e1f = fabsf(__fsub_rn(x1, __fmul_rn(0.01f, ff1 + 0.5f)));
    e0f = ((unsigned)f0 < (unsigned)BINS) ? e0f : 1e9f;
    e1f = ((unsigned)f1 < (unsigned)BINS) ? e1f : 1e9f;
    const int rm = max(i0 - 1, 0) * BINS;
    const int r0 = i0 * BINS;
    const int rp = min(i0 + 1, BINS - 1) * BINS;
    const int rf = min(max(f0, 0), BINS - 1) * BINS;
    const int cm = max(i1 - 1, 0);
    const int cc = i1;
    const int cp = min(i1 + 1, BINS - 1);
    const int cf = min(max(f1, 0), BINS - 1);
#define SITEF(EA, EB, ADDR) do {                                               \
        const float w_ = fmaf(-0.5f, __fadd_rn(EA, EB), 0.01f);                \
        if (w_ > 0.0f) unsafeAtomicAdd(&lh[ADDR], w_);                         \
    } while (0)
    SITEF(e0m, e1m, rm + cm); SITEF(e0m, e10, rm + cc); SITEF(e0m, e1p, rm + cp);
    SITEF(e00, e1m, r0 + cm); SITEF(e00, e10, r0 + cc); SITEF(e00, e1p, r0 + cp);
    SITEF(e0p, e1m, rp + cm); SITEF(e0p, e10, rp + cc); SITEF(e0p, e1p, rp + cp);
    SITEF(e0f, e10, rf + cc);
    SITEF(e00, e1f, r0 + cf);
#undef SITEF
}

__global__ __launch_bounds__(THREADS) void hist_accum_kernel(
    const float* __restrict__ x, float* __restrict__ out)
{
    __shared__ __align__(16) float lh[NBINS2];
    float4* lh4 = (float4*)lh;
    for (int i = threadIdx.x; i < NBINS2 / 4; i += THREADS)
        lh4[i] = make_float4(0.f, 0.f, 0.f, 0.f);
    __syncthreads();
    const int b  = blockIdx.x / PPB;
    const int pb = blockIdx.x % PPB;
    const float4* __restrict__ xp = reinterpret_cast<const float4*>(
        x + (size_t)b * (NPOINTS * 2) + (size_t)pb * (CHUNK * 2));
    #pragma unroll
    for (int k = 0; k < (CHUNK / 2) / THREADS; ++k) {
        const float4 p = xp[threadIdx.x + k * THREADS];
        accum_point_f(lh, p.x, p.y);
        accum_point_f(lh, p.z, p.w);
    }
    __syncthreads();
    float* __restrict__ ob = out + (size_t)b * NBINS2;
    for (int i = threadIdx.x; i < NBINS2; i += THREADS) {
        const float v = lh[i];
        if (v != 0.0f) unsafeAtomicAdd(&ob[i], v);
    }
}

__global__ __launch_bounds__(1024) void norm_kernel(float* __restrict__ out)
{
    const int b = blockIdx.x;
    float* __restrict__ h = out + (size_t)b * NBINS2;
    float local = 0.0f;
    for (int i = threadIdx.x; i < NBINS2; i += 1024) local += h[i];
    #pragma unroll
    for (int off = 32; off > 0; off >>= 1) local += __shfl_down(local, off, 64);
    __shared__ float wsum[16];
    __shared__ float sden;
    if ((threadIdx.x & 63) == 0) wsum[threadIdx.x >> 6] = local;
    __syncthreads();
    if (threadIdx.x == 0) {
        float tt = 0.f;
        #pragma unroll
        for (int i = 0; i < 16; ++i) tt += wsum[i];
        sden = __fadd_rn(tt, 1e-5f);
    }
    __syncthreads();
    const float den = sden;
    for (int i = threadIdx.x; i < NBINS2; i += 1024) h[i] = __fdiv_rn(h[i], den);
}

extern "C" void kernel_launch(void* const* d_in, const int* in_sizes, int n_in,
                              void* d_out, int out_size, void* d_ws, size_t ws_size,
                              hipStream_t stream) {
    (void)in_sizes; (void)n_in;
    const float* x = (const float*)d_in[0];
    float* out = (float*)d_out;

    // ws layout: [0,128) totals u64[16]; [128, 128+640000) accum u32[16][10000]
    const size_t need = 128 + (size_t)NBATCH * NBINS2 * sizeof(unsigned);
    if (ws_size >= need) {
        unsigned long long* totals = (unsigned long long*)d_ws;
        unsigned* accum = (unsigned*)((char*)d_ws + 128);
        hipMemsetAsync(d_ws, 0, need, stream);
        hist_part_kernel<<<NPART, THREADS, 0, stream>>>(x, accum, totals);
        reduce_norm_kernel<<<NBATCH * 10, 256, 0, stream>>>(
            (const uint4*)accum, totals, (float4*)out);
    } else {
        hipMemsetAsync(out, 0, (size_t)out_size * sizeof(float), stream);
        hist_accum_kernel<<<NPART, THREADS, 0, stream>>>(x, out);
        norm_kernel<<<NBATCH, 1024, 0, stream>>>(out);
    }
}

// Round 10
// 144.275 us; speedup vs baseline: 2.4155x; 1.0467x over previous
//
#include <hip/hip_runtime.h>

// Histogram2D: x (16, 131072, 2) f32 in [0,1) -> counts (16, 100, 100) f32, normalized.
// Round 10: A/B isolating the site-masking form. r4 (ALL-masked) inferred hist ~66us vs
// r5/r9 (5-uncond) profiled 89.7/90us at identical fired-lane counts -> revert the
// plus-shape to masked if(w>0) (r4 form). Structure otherwise identical to r9:
// LDS u32 hist (quantum 2^-25) -> coalesced u64-pair atomic flush into per-batch
// 640KB accum (L2/MALL-resident) + exact in-hist u64 totals -> tiny reduce_norm.

#define BINS     100
#define NBINS2   (BINS * BINS)     // 10000
#define NPAIR    (NBINS2 / 2)      // 5000 u64 bin-pairs
#define NPOINTS  131072
#define NBATCH   16
#define PPB      32                // partial blocks per batch
#define CHUNK    (NPOINTS / PPB)   // 4096 points per block
#define THREADS  1024
#define NPART    (NBATCH * PPB)    // 512
#define QSCALE   33554432.0f       // 2^25 fixed-point scale
#define QINV     (1.0 / 33554432.0)

__device__ __forceinline__ void accum_point_q(unsigned* lh, float x0, float x1) {
    // anchor bin: floor(x*100) clipped (verified numerics, r4-r9)
    int i0 = __float2int_rd(__fmul_rn(x0, 100.0f)); i0 = min(max(i0, 0), BINS - 1);
    int i1 = __float2int_rd(__fmul_rn(x1, 100.0f)); i1 = min(max(i1, 0), BINS - 1);
    const float fi0 = (float)i0, fi1 = (float)i1;
    const float c00 = __fmul_rn(0.01f, fi0 + 0.5f);
    const float c10 = __fmul_rn(0.01f, fi1 + 0.5f);
    const float e00 = fabsf(__fsub_rn(x0, c00));
    const float e10 = fabsf(__fsub_rn(x1, c10));
    float e0m = fabsf(__fsub_rn(x0, __fmul_rn(0.01f, fi0 - 0.5f)));
    float e0p = fabsf(__fsub_rn(x0, __fmul_rn(0.01f, fi0 + 1.5f)));
    float e1m = fabsf(__fsub_rn(x1, __fmul_rn(0.01f, fi1 - 0.5f)));
    float e1p = fabsf(__fsub_rn(x1, __fmul_rn(0.01f, fi1 + 1.5f)));
    e0m = (i0 > 0)        ? e0m : 1e9f;   // OOB -> w < 0 -> masked off
    e0p = (i0 < BINS - 1) ? e0p : 1e9f;
    e1m = (i1 > 0)        ? e1m : 1e9f;
    e1p = (i1 < BINS - 1) ? e1p : 1e9f;
    // only the leaned-toward +/-2 offset can fire, paired with the other coord's own bin
    const bool up0 = (x0 > c00), up1 = (x1 > c10);
    const int   f0  = up0 ? i0 + 2 : i0 - 2;
    const int   f1  = up1 ? i1 + 2 : i1 - 2;
    const float ff0 = up0 ? fi0 + 2.0f : fi0 - 2.0f;
    const float ff1 = up1 ? fi1 + 2.0f : fi1 - 2.0f;
    float e0f = fabsf(__fsub_rn(x0, __fmul_rn(0.01f, ff0 + 0.5f)));
    float e1f = fabsf(__fsub_rn(x1, __fmul_rn(0.01f, ff1 + 0.5f)));
    e0f = ((unsigned)f0 < (unsigned)BINS) ? e0f : 1e9f;
    e1f = ((unsigned)f1 < (unsigned)BINS) ? e1f : 1e9f;

    const int rm = max(i0 - 1, 0) * BINS;
    const int r0 = i0 * BINS;
    const int rp = min(i0 + 1, BINS - 1) * BINS;
    const int rf = min(max(f0, 0), BINS - 1) * BINS;
    const int cm = max(i1 - 1, 0);
    const int cc = i1;
    const int cp = min(i1 + 1, BINS - 1);
    const int cf = min(max(f1, 0), BINS - 1);

    // ALL sites masked (r4 form): only fired lanes touch the LDS atomic engine
#define SITEQ(EA, EB, ADDR) do {                                               \
        const float w_ = fmaf(-0.5f, __fadd_rn(EA, EB), 0.01f);                \
        if (w_ > 0.0f)                                                         \
            atomicAdd(&lh[ADDR], (unsigned)fmaf(w_, QSCALE, 0.5f));            \
    } while (0)
    SITEQ(e0m, e1m, rm + cm); SITEQ(e0m, e10, rm + cc); SITEQ(e0m, e1p, rm + cp);
    SITEQ(e00, e1m, r0 + cm); SITEQ(e00, e10, r0 + cc); SITEQ(e00, e1p, r0 + cp);
    SITEQ(e0p, e1m, rp + cm); SITEQ(e0p, e10, rp + cc); SITEQ(e0p, e1p, rp + cp);
    SITEQ(e0f, e10, rf + cc);
    SITEQ(e00, e1f, r0 + cf);
#undef SITEQ
}

// ---- main path: LDS u32 hist -> COALESCED u64-pair atomic flush into per-batch
// accumulator (640KB total) + exact u64 batch totals ----
__global__ __launch_bounds__(THREADS) void hist_part_kernel(
    const float* __restrict__ x, unsigned* __restrict__ accum,
    unsigned long long* __restrict__ totals)
{
    __shared__ __align__(16) unsigned lh[NBINS2];
    uint4* lh4 = (uint4*)lh;
    for (int i = threadIdx.x; i < NBINS2 / 4; i += THREADS)
        lh4[i] = make_uint4(0u, 0u, 0u, 0u);
    __syncthreads();

    const int b  = blockIdx.x / PPB;
    const int pb = blockIdx.x % PPB;
    const float4* __restrict__ xp = reinterpret_cast<const float4*>(
        x + (size_t)b * (NPOINTS * 2) + (size_t)pb * (CHUNK * 2));

    #pragma unroll
    for (int k = 0; k < (CHUNK / 2) / THREADS; ++k) {
        const float4 p = xp[threadIdx.x + k * THREADS];
        accum_point_q(lh, p.x, p.y);
        accum_point_q(lh, p.z, p.w);
    }
    __syncthreads();

    // flush: 5000 coalesced u64 atomics per block into the batch's accum row.
    const uint2* __restrict__ lh2 = (const uint2*)lh;
    unsigned long long* __restrict__ acc2 =
        (unsigned long long*)(accum + (size_t)b * NBINS2);
    unsigned long long ts = 0ull;
    for (int i = threadIdx.x; i < NPAIR; i += THREADS) {
        const uint2 v = lh2[i];
        const unsigned long long pk =
            (unsigned long long)v.x | ((unsigned long long)v.y << 32);
        if (pk) atomicAdd(&acc2[i], pk);
        ts += (unsigned long long)v.x + v.y;
    }
    #pragma unroll
    for (int off = 32; off > 0; off >>= 1) ts += __shfl_down(ts, off, 64);
    if ((threadIdx.x & 63) == 0) atomicAdd(&totals[b], ts);
}

// 160 blocks x 256 thr: (b = blk/10, chunk = blk%10); one uint4 (4 bins)/thread.
__global__ __launch_bounds__(256) void reduce_norm_kernel(
    const uint4* __restrict__ accum4, const unsigned long long* __restrict__ totals,
    float4* __restrict__ out4)
{
    const int b  = blockIdx.x / 10;
    const int ch = blockIdx.x % 10;
    const int t  = threadIdx.x;
    if (t < 250) {   // 250 uint4 = 1000 bins per chunk
        const int idx = b * (NBINS2 / 4) + ch * 250 + t;
        const uint4 v = accum4[idx];
        const double fac = QINV / ((double)totals[b] * QINV + 1e-5);
        out4[idx] = make_float4(
            (float)((double)v.x * fac), (float)((double)v.y * fac),
            (float)((double)v.z * fac), (float)((double)v.w * fac));
    }
}

// ---- fallback path (ws too small): float LDS hist + global atomic flush ----
__device__ __forceinline__ void accum_point_f(float* lh, float x0, float x1) {
    int i0 = __float2int_rd(__fmul_rn(x0, 100.0f)); i0 = min(max(i0, 0), BINS - 1);
    int i1 = __float2int_rd(__fmul_rn(x1, 100.0f)); i1 = min(max(i1, 0), BINS - 1);
    const float fi0 = (float)i0, fi1 = (float)i1;
    const float c00 = __fmul_rn(0.01f, fi0 + 0.5f);
    const float c10 = __fmul_rn(0.01f, fi1 + 0.5f);
    const float e00 = fabsf(__fsub_rn(x0, c00));
    const float e10 = fabsf(__fsub_rn(x1, c10));
    float e0m = fabsf(__fsub_rn(x0, __fmul_rn(0.01f, fi0 - 0.5f)));
    float e0p = fabsf(__fsub_rn(x0, __fmul_rn(0.01f, fi0 + 1.5f)));
    float e1m = fabsf(__fsub_rn(x1, __fmul_rn(0.01f, fi1 - 0.5f)));
    float e1p = fabsf(__fsub_rn(x1, __fmul_rn(0.01f, fi1 + 1.5f)));
    e0m = (i0 > 0)        ? e0m : 1e9f;
    e0p = (i0 < BINS - 1) ? e0p : 1e9f;
    e1m = (i1 > 0)        ? e1m : 1e9f;
    e1p = (i1 < BINS - 1) ? e1p : 1e9f;
    const bool up0 = (x0 > c00), up1 = (x1 > c10);
    const int   f0  = up0 ? i0 + 2 : i0 - 2;
    const int   f1  = up1 ? i1 + 2 : i1 - 2;
    const float ff0 = up0 ? fi0 + 2.0f : fi0 - 2.0f;
    const float ff1 = up1 ? fi1 + 2.0f : fi1 - 2.0f;
    float e0f = fabsf(__fsub_rn(x0, __fmul_rn(0.01f, ff0 + 0.5f)));
    float e1f = fabsf(__fsub_rn(x1, __fmul_rn(0.01f, ff1 + 0.5f)));
    e0f = ((unsigned)f0 < (unsigned)BINS) ? e0f : 1e9f;
    e1f = ((unsigned)f1 < (unsigned)BINS) ? e1f : 1e9f;
    const int rm = max(i0 - 1, 0) * BINS;
    const int r0 = i0 * BINS;
    const int rp = min(i0 + 1, BINS - 1) * BINS;
    const int rf = min(max(f0, 0), BINS - 1) * BINS;
    const int cm = max(i1 - 1, 0);
    const int cc = i1;
    const int cp = min(i1 + 1, BINS - 1);
    const int cf = min(max(f1, 0), BINS - 1);
#define SITEF(EA, EB, ADDR) do {                                               \
        const float w_ = fmaf(-0.5f, __fadd_rn(EA, EB), 0.01f);                \
        if (w_ > 0.0f) unsafeAtomicAdd(&lh[ADDR], w_);                         \
    } while (0)
    SITEF(e0m, e1m, rm + cm); SITEF(e0m, e10, rm + cc); SITEF(e0m, e1p, rm + cp);
    SITEF(e00, e1m, r0 + cm); SITEF(e00, e10, r0 + cc); SITEF(e00, e1p, r0 + cp);
    SITEF(e0p, e1m, rp + cm); SITEF(e0p, e10, rp + cc); SITEF(e0p, e1p, rp + cp);
    SITEF(e0f, e10, rf + cc);
    SITEF(e00, e1f, r0 + cf);
#undef SITEF
}

__global__ __launch_bounds__(THREADS) void hist_accum_kernel(
    const float* __restrict__ x, float* __restrict__ out)
{
    __shared__ __align__(16) float lh[NBINS2];
    float4* lh4 = (float4*)lh;
    for (int i = threadIdx.x; i < NBINS2 / 4; i += THREADS)
        lh4[i] = make_float4(0.f, 0.f, 0.f, 0.f);
    __syncthreads();
    const int b  = blockIdx.x / PPB;
    const int pb = blockIdx.x % PPB;
    const float4* __restrict__ xp = reinterpret_cast<const float4*>(
        x + (size_t)b * (NPOINTS * 2) + (size_t)pb * (CHUNK * 2));
    #pragma unroll
    for (int k = 0; k < (CHUNK / 2) / THREADS; ++k) {
        const float4 p = xp[threadIdx.x + k * THREADS];
        accum_point_f(lh, p.x, p.y);
        accum_point_f(lh, p.z, p.w);
    }
    __syncthreads();
    float* __restrict__ ob = out + (size_t)b * NBINS2;
    for (int i = threadIdx.x; i < NBINS2; i += THREADS) {
        const float v = lh[i];
        if (v != 0.0f) unsafeAtomicAdd(&ob[i], v);
    }
}

__global__ __launch_bounds__(1024) void norm_kernel(float* __restrict__ out)
{
    const int b = blockIdx.x;
    float* __restrict__ h = out + (size_t)b * NBINS2;
    float local = 0.0f;
    for (int i = threadIdx.x; i < NBINS2; i += 1024) local += h[i];
    #pragma unroll
    for (int off = 32; off > 0; off >>= 1) local += __shfl_down(local, off, 64);
    __shared__ float wsum[16];
    __shared__ float sden;
    if ((threadIdx.x & 63) == 0) wsum[threadIdx.x >> 6] = local;
    __syncthreads();
    if (threadIdx.x == 0) {
        float tt = 0.f;
        #pragma unroll
        for (int i = 0; i < 16; ++i) tt += wsum[i];
        sden = __fadd_rn(tt, 1e-5f);
    }
    __syncthreads();
    const float den = sden;
    for (int i = threadIdx.x; i < NBINS2; i += 1024) h[i] = __fdiv_rn(h[i], den);
}

extern "C" void kernel_launch(void* const* d_in, const int* in_sizes, int n_in,
                              void* d_out, int out_size, void* d_ws, size_t ws_size,
                              hipStream_t stream) {
    (void)in_sizes; (void)n_in;
    const float* x = (const float*)d_in[0];
    float* out = (float*)d_out;

    // ws layout: [0,128) totals u64[16]; [128, 128+640000) accum u32[16][10000]
    const size_t need = 128 + (size_t)NBATCH * NBINS2 * sizeof(unsigned);
    if (ws_size >= need) {
        unsigned long long* totals = (unsigned long long*)d_ws;
        unsigned* accum = (unsigned*)((char*)d_ws + 128);
        hipMemsetAsync(d_ws, 0, need, stream);
        hist_part_kernel<<<NPART, THREADS, 0, stream>>>(x, accum, totals);
        reduce_norm_kernel<<<NBATCH * 10, 256, 0, stream>>>(
            (const uint4*)accum, totals, (float4*)out);
    } else {
        hipMemsetAsync(out, 0, (size_t)out_size * sizeof(float), stream);
        hist_accum_kernel<<<NPART, THREADS, 0, stream>>>(x, out);
        norm_kernel<<<NBATCH, 1024, 0, stream>>>(out);
    }
}